// Round 2
// baseline (2662.227 us; speedup 1.0000x reference)
//
#include <hip/hip_runtime.h>

#define B_   4
#define T_   2048
#define C_   1024
#define QD   256
#define KVD  32
#define NR   (B_*T_)          // 8192 rows
#define EPSF 1e-5f
#define CAPS 64.0f
#define INV_SS (1.0f/1024.0f)

// ---------- dtype helpers (runtime-flagged) ----------
__device__ __forceinline__ float bf2f(unsigned short h) {
    return __uint_as_float(((unsigned)h) << 16);
}
__device__ __forceinline__ unsigned short f2bf(float f) {
    unsigned u = __float_as_uint(f);
    u = u + 0x7fffu + ((u >> 16) & 1u);   // round-to-nearest-even
    return (unsigned short)(u >> 16);
}
__device__ __forceinline__ float ldf(const void* p, long i, int isbf) {
    return isbf ? bf2f(((const unsigned short*)p)[i]) : ((const float*)p)[i];
}
__device__ __forceinline__ long ldix(const void* p, long i, int is64) {
    return is64 ? (long)((const long long*)p)[i] : (long)((const int*)p)[i];
}

// ---------- dtype detection ----------
// x ~ N(0,1): if bf16, sampled u16s are bf16 values with exponent near 127.
// If f32, even u16 indices are mantissa-low halves -> ~uniform exponents.
// idx: if int64 (values < 2^31), every odd u32 is 0.
__global__ void detect_kernel(const void* x, const void* idxp, int* flags) {
    __shared__ int cnt[2];
    int tid = threadIdx.x;
    if (tid < 2) cnt[tid] = 0;
    __syncthreads();
    int pl = 0;
    const unsigned short* u = (const unsigned short*)x;
    for (int r = 0; r < 2; r++) {
        long j = 2L * (((long)(tid * 2 + r) * 15013L) % 4000000L);
        unsigned short v = u[j];
        int e = (v >> 7) & 0xff;
        pl += (v == 0 || (e >= 100 && e <= 140)) ? 1 : 0;
    }
    atomicAdd(&cnt[0], pl);
    const unsigned* w = (const unsigned*)idxp;
    int z = (w[2 * tid + 1] == 0u) ? 1 : 0;
    atomicAdd(&cnt[1], z);
    __syncthreads();
    if (tid == 0) {
        flags[0] = (cnt[0] > 384) ? 1 : 0;   // float tensors are bf16
        flags[1] = (cnt[1] > 128) ? 1 : 0;   // idx is int64
    }
}

// ---------- tiled GEMM: C[M,N] = act(A[M,K] @ W[N,K]^T) (* emb gather) ----------
// BM=64, BK=32, BN in {32,64}. 256 threads, micro-tile 4 x TN.
template<int BN, int TANH, int EMB>
__global__ __launch_bounds__(256) void gemm_kernel(
    const void* __restrict__ A, const void* __restrict__ W,
    const void* __restrict__ emb, const void* __restrict__ idxp,
    float* __restrict__ Cout, int M, int K, int N, int embN, int amode,
    const int* __restrict__ flags)
{
    const int fbf = flags[0];
    const int abf = amode ? fbf : 0;
    const int i64 = flags[1];

    __shared__ float As[32][68];
    __shared__ float Bs[32][BN + 4];

    const int tid = threadIdx.x;
    const long m0 = (long)blockIdx.x * 64;
    const int  n0 = blockIdx.y * BN;
    constexpr int TN = (BN == 64) ? 4 : 2;
    const int tx = tid & 15;    // col group
    const int ty = tid >> 4;    // row group

    float c[4][TN];
#pragma unroll
    for (int i = 0; i < 4; i++)
#pragma unroll
        for (int j = 0; j < TN; j++) c[i][j] = 0.0f;

    for (int k0 = 0; k0 < K; k0 += 32) {
        // stage A tile 64x32 (transposed into LDS)
        {
            int i = tid >> 2;
            int j0 = (tid & 3) * 8;
            long base = (m0 + i) * (long)K + k0 + j0;
#pragma unroll
            for (int jj = 0; jj < 8; jj++) As[j0 + jj][i] = ldf(A, base + jj, abf);
        }
        // stage B tile BKxBN from W[N][K]
        if (BN == 64) {
            int n = tid >> 2;
            int j0 = (tid & 3) * 8;
            long base = (long)(n0 + n) * K + k0 + j0;
#pragma unroll
            for (int jj = 0; jj < 8; jj++) Bs[j0 + jj][n] = ldf(W, base + jj, fbf);
        } else {
            int n = tid >> 3;
            int j0 = (tid & 7) * 4;
            long base = (long)(n0 + n) * K + k0 + j0;
#pragma unroll
            for (int jj = 0; jj < 4; jj++) Bs[j0 + jj][n] = ldf(W, base + jj, fbf);
        }
        __syncthreads();
#pragma unroll
        for (int kk = 0; kk < 32; kk++) {
            const float4 af = *reinterpret_cast<const float4*>(&As[kk][ty * 4]);
            const float av[4] = {af.x, af.y, af.z, af.w};
            float bv[TN];
#pragma unroll
            for (int j = 0; j < TN; j++) bv[j] = Bs[kk][tx * TN + j];
#pragma unroll
            for (int i = 0; i < 4; i++)
#pragma unroll
                for (int j = 0; j < TN; j++) c[i][j] = fmaf(av[i], bv[j], c[i][j]);
        }
        __syncthreads();
    }

#pragma unroll
    for (int i = 0; i < 4; i++) {
        long row = m0 + ty * 4 + i;
        long id = 0;
        if (EMB) id = ldix(idxp, row, i64);
#pragma unroll
        for (int j = 0; j < TN; j++) {
            int col = n0 + tx * TN + j;
            float v = c[i][j];
            if (TANH) v = tanhf(v);
            if (EMB)  v *= ldf(emb, id * (long)embN + col, fbf);
            Cout[row * (long)N + col] = v;
        }
    }
}

// ---------- fused time-shift + LayerNorm ----------
// m = src[t] + (src[t-1] - src[t]) * xs  (src[-1] = 0), then LN(m)*g + b.
template<int DIM>
__global__ __launch_bounds__(256) void shiftln_kernel(
    const float* __restrict__ src, void* __restrict__ dst, int dst_bf16,
    const void* __restrict__ xs, const void* __restrict__ g,
    const void* __restrict__ bb, const int* __restrict__ flags)
{
    const int fbf = flags[0];
    const long r = blockIdx.x;
    const int t = (int)(r % T_);
    const int tid = threadIdx.x;
    constexpr int PT = DIM / 256;
    float m[PT];
    float s1 = 0.0f, s2 = 0.0f;
#pragma unroll
    for (int j = 0; j < PT; j++) {
        int o = tid + 256 * j;
        float v  = src[r * DIM + o];
        float pv = (t > 0) ? src[(r - 1) * DIM + o] : 0.0f;
        float xv = ldf(xs, o, fbf);
        float mm = v + (pv - v) * xv;
        m[j] = mm;
        s1 += mm;
        s2 += mm * mm;
    }
#pragma unroll
    for (int off = 32; off > 0; off >>= 1) {
        s1 += __shfl_xor(s1, off);
        s2 += __shfl_xor(s2, off);
    }
    __shared__ float r1[4], r2[4];
    int w = tid >> 6;
    if ((tid & 63) == 0) { r1[w] = s1; r2[w] = s2; }
    __syncthreads();
    float t1 = r1[0] + r1[1] + r1[2] + r1[3];
    float t2 = r2[0] + r2[1] + r2[2] + r2[3];
    float mean = t1 / (float)DIM;
    float var  = t2 / (float)DIM - mean * mean;
    float rs = rsqrtf(var + EPSF);
#pragma unroll
    for (int j = 0; j < PT; j++) {
        int o = tid + 256 * j;
        float y = (m[j] - mean) * rs * ldf(g, o, fbf) + ldf(bb, o, fbf);
        if (dst_bf16) ((unsigned short*)dst)[r * DIM + o] = f2bf(y);
        else          ((float*)dst)[r * DIM + o] = y;
    }
}

// ---------- causal attention, one pass (scores bounded by +-64 => no max sub) ----------
// 256 threads = 4 waves; 16 queries/block (4 per wave); key tiles of 16 in LDS.
#define KT 16
#define QB 16
__global__ __launch_bounds__(256) void attn_kernel(
    const float* __restrict__ q, const float* __restrict__ k,
    const unsigned* __restrict__ vpak, float* __restrict__ out)
{
    __shared__ float    ks[KT][260];
    __shared__ unsigned vs[KT][512];

    const int tid = threadIdx.x;
    const int w = tid >> 6;
    const int l = tid & 63;
    const int nb = T_ / QB;                 // 128
    const int b  = blockIdx.x / nb;
    const int tb = blockIdx.x % nb;
    const int t0 = (nb - 1 - tb) * QB;      // reversed: big-work blocks first

    float4 qr[4];
#pragma unroll
    for (int qi = 0; qi < 4; qi++) {
        long row = (long)b * T_ + t0 + w * 4 + qi;
        qr[qi] = *reinterpret_cast<const float4*>(&q[row * QD + 4 * l]);
    }

    float acc[4][16];
#pragma unroll
    for (int qi = 0; qi < 4; qi++)
#pragma unroll
        for (int j = 0; j < 16; j++) acc[qi][j] = 0.0f;
    float den[4] = {0.f, 0.f, 0.f, 0.f};

    const int tmax = t0 + QB - 1;
    for (int st0 = 0; st0 <= tmax; st0 += KT) {
        __syncthreads();
        {   // stage k tile: 16 rows x 256 f32
            int rr = tid >> 4;
            int c0 = (tid & 15) * 16;
            const float* src = &k[((long)b * T_ + st0 + rr) * QD + c0];
            float4* dstp = reinterpret_cast<float4*>(&ks[rr][c0]);
#pragma unroll
            for (int u = 0; u < 4; u++)
                dstp[u] = *reinterpret_cast<const float4*>(&src[4 * u]);
        }
        {   // stage v tile: 16 rows x 512 u32 (bf16 pairs)
            int rr = tid >> 4;
            int c0 = (tid & 15) * 32;
            const uint4* sp = reinterpret_cast<const uint4*>(
                &vpak[((long)b * T_ + st0 + rr) * 512 + c0]);
            uint4* dstp = reinterpret_cast<uint4*>(&vs[rr][c0]);
#pragma unroll
            for (int u = 0; u < 8; u++) dstp[u] = sp[u];
        }
        __syncthreads();

        for (int s = 0; s < KT; s++) {
            const int sa = st0 + s;
            const float4 kk = *reinterpret_cast<const float4*>(&ks[s][4 * l]);
            float p[4];
#pragma unroll
            for (int qi = 0; qi < 4; qi++) {
                float4 a = qr[qi];
                float d = a.x * kk.x;
                d = fmaf(a.y, kk.y, d);
                d = fmaf(a.z, kk.z, d);
                d = fmaf(a.w, kk.w, d);
                p[qi] = d;
            }
#pragma unroll
            for (int off = 32; off > 0; off >>= 1) {
#pragma unroll
                for (int qi = 0; qi < 4; qi++) p[qi] += __shfl_xor(p[qi], off);
            }
            float wv[4];
#pragma unroll
            for (int qi = 0; qi < 4; qi++) {
                int tq = t0 + w * 4 + qi;
                float sc = CAPS * tanhf(p[qi] * INV_SS);
                wv[qi] = (sa <= tq) ? __expf(sc) : 0.0f;
                den[qi] += wv[qi];
            }
#pragma unroll
            for (int j = 0; j < 8; j++) {
                unsigned u = vs[s][l + 64 * j];
                float lo = __uint_as_float(u << 16);
                float hi = __uint_as_float(u & 0xffff0000u);
#pragma unroll
                for (int qi = 0; qi < 4; qi++) {
                    acc[qi][2 * j]     = fmaf(wv[qi], lo, acc[qi][2 * j]);
                    acc[qi][2 * j + 1] = fmaf(wv[qi], hi, acc[qi][2 * j + 1]);
                }
            }
        }
    }

    // f32 output: channel pair (2l + 128j, 2l + 128j + 1) per lane
#pragma unroll
    for (int qi = 0; qi < 4; qi++) {
        long row = (long)b * T_ + t0 + w * 4 + qi;
        float inv = 1.0f / den[qi];
        float* op = out + row * (long)C_;
#pragma unroll
        for (int j = 0; j < 8; j++) {
            float2 val;
            val.x = acc[qi][2 * j] * inv;
            val.y = acc[qi][2 * j + 1] * inv;
            *reinterpret_cast<float2*>(&op[2 * l + 128 * j]) = val;
        }
    }
}

// ---------- launch ----------
extern "C" void kernel_launch(void* const* d_in, const int* in_sizes, int n_in,
                              void* d_out, int out_size, void* d_ws, size_t ws_size,
                              hipStream_t stream) {
    const void* x       = d_in[0];
    const void* idx     = d_in[1];
    const void* W_qq    = d_in[2];
    const void* W_k     = d_in[3];
    const void* W_kup   = d_in[4];
    const void* W_v     = d_in[5];
    const void* W_vup   = d_in[6];
    const void* k_emb   = d_in[7];
    const void* v_emb   = d_in[8];
    const void* x_q     = d_in[9];
    const void* x_k     = d_in[10];
    const void* x_v     = d_in[11];
    const void* g_q     = d_in[12];
    const void* b_q     = d_in[13];
    const void* g_k     = d_in[14];
    const void* b_k     = d_in[15];
    const void* g_v     = d_in[16];
    const void* b_v     = d_in[17];

    char* p = (char*)d_ws;
    int*   flags = (int*)p;            p += 256;
    float* qraw  = (float*)p;          p += (size_t)NR * QD * 4;     // 8 MB
    float* kd    = (float*)p;          p += (size_t)NR * KVD * 4;    // 1 MB
    float* vd    = (float*)p;          p += (size_t)NR * KVD * 4;    // 1 MB
    float* kraw  = (float*)p;          p += (size_t)NR * QD * 4;     // 8 MB
    float* vraw  = (float*)p;          p += (size_t)NR * C_ * 4;     // 32 MB
    float* qf    = (float*)p;          p += (size_t)NR * QD * 4;     // 8 MB
    float* kf    = (float*)p;          p += (size_t)NR * QD * 4;     // 8 MB
    unsigned* vpak = (unsigned*)p;     p += (size_t)NR * (C_ / 2) * 4; // 16 MB

    detect_kernel<<<1, 256, 0, stream>>>(x, idx, flags);

    // q_raw = x @ W_qq^T                       [8192,1024] x [1024->256]
    gemm_kernel<64, 0, 0><<<dim3(NR / 64, QD / 64), 256, 0, stream>>>(
        x, W_qq, nullptr, nullptr, qraw, NR, C_, QD, 0, 1, flags);
    // kd = x @ W_k^T                           [8192,1024] x [1024->32]
    gemm_kernel<32, 0, 0><<<dim3(NR / 64, 1), 256, 0, stream>>>(
        x, W_k, nullptr, nullptr, kd, NR, C_, KVD, 0, 1, flags);
    // vd = x @ W_v^T
    gemm_kernel<32, 0, 0><<<dim3(NR / 64, 1), 256, 0, stream>>>(
        x, W_v, nullptr, nullptr, vd, NR, C_, KVD, 0, 1, flags);
    // k_raw = (kd @ W_kup^T) * k_emb[idx]      [8192,32] x [32->256]
    gemm_kernel<64, 0, 1><<<dim3(NR / 64, QD / 64), 256, 0, stream>>>(
        kd, W_kup, k_emb, idx, kraw, NR, KVD, QD, QD, 0, flags);
    // v_raw = tanh(vd @ W_vup^T) * v_emb[idx]  [8192,32] x [32->1024]
    gemm_kernel<64, 1, 1><<<dim3(NR / 64, C_ / 64), 256, 0, stream>>>(
        vd, W_vup, v_emb, idx, vraw, NR, KVD, C_, C_, 0, flags);

    shiftln_kernel<QD><<<NR, 256, 0, stream>>>(qraw, qf,   0, x_q, g_q, b_q, flags);
    shiftln_kernel<QD><<<NR, 256, 0, stream>>>(kraw, kf,   0, x_k, g_k, b_k, flags);
    shiftln_kernel<C_><<<NR, 256, 0, stream>>>(vraw, vpak, 1, x_v, g_v, b_v, flags);

    attn_kernel<<<B_ * (T_ / QB), 256, 0, stream>>>(qf, kf, vpak, (float*)d_out);
}

// Round 3
// 920.425 us; speedup vs baseline: 2.8924x; 2.8924x over previous
//
#include <hip/hip_runtime.h>

#define B_   4
#define T_   2048
#define C_   1024
#define QD   256
#define KVD  32
#define NR   (B_*T_)          // 8192 rows
#define EPSF 1e-5f
#define CAPS 64.0f
#define INV_SS (1.0f/1024.0f)

typedef __attribute__((ext_vector_type(8))) short bf16x8;
typedef __attribute__((ext_vector_type(4))) float f32x4;

// ---------- dtype helpers (runtime-flagged) ----------
__device__ __forceinline__ float bf2f(unsigned short h) {
    return __uint_as_float(((unsigned)h) << 16);
}
__device__ __forceinline__ unsigned short f2bf(float f) {
    unsigned u = __float_as_uint(f);
    u = u + 0x7fffu + ((u >> 16) & 1u);   // round-to-nearest-even
    return (unsigned short)(u >> 16);
}
__device__ __forceinline__ float ldf(const void* p, long i, int isbf) {
    return isbf ? bf2f(((const unsigned short*)p)[i]) : ((const float*)p)[i];
}
__device__ __forceinline__ long ldix(const void* p, long i, int is64) {
    return is64 ? (long)((const long long*)p)[i] : (long)((const int*)p)[i];
}

// ---------- dtype detection ----------
__global__ void detect_kernel(const void* x, const void* idxp, int* flags) {
    __shared__ int cnt[2];
    int tid = threadIdx.x;
    if (tid < 2) cnt[tid] = 0;
    __syncthreads();
    int pl = 0;
    const unsigned short* u = (const unsigned short*)x;
    for (int r = 0; r < 2; r++) {
        long j = 2L * (((long)(tid * 2 + r) * 15013L) % 4000000L);
        unsigned short v = u[j];
        int e = (v >> 7) & 0xff;
        pl += (v == 0 || (e >= 100 && e <= 140)) ? 1 : 0;
    }
    atomicAdd(&cnt[0], pl);
    const unsigned* w = (const unsigned*)idxp;
    int z = (w[2 * tid + 1] == 0u) ? 1 : 0;
    atomicAdd(&cnt[1], z);
    __syncthreads();
    if (tid == 0) {
        flags[0] = (cnt[0] > 384) ? 1 : 0;   // float tensors are bf16
        flags[1] = (cnt[1] > 128) ? 1 : 0;   // idx is int64
    }
}

// ---------- tiled GEMM: C[M,N] = act(A[M,K] @ W[N,K]^T) (* emb gather) ----------
template<int BN, int TANH, int EMB>
__global__ __launch_bounds__(256) void gemm_kernel(
    const void* __restrict__ A, const void* __restrict__ W,
    const void* __restrict__ emb, const void* __restrict__ idxp,
    float* __restrict__ Cout, int M, int K, int N, int embN, int amode,
    const int* __restrict__ flags)
{
    const int fbf = flags[0];
    const int abf = amode ? fbf : 0;
    const int i64 = flags[1];

    __shared__ float As[32][68];
    __shared__ float Bs[32][BN + 4];

    const int tid = threadIdx.x;
    const long m0 = (long)blockIdx.x * 64;
    const int  n0 = blockIdx.y * BN;
    constexpr int TN = (BN == 64) ? 4 : 2;
    const int tx = tid & 15;
    const int ty = tid >> 4;

    float c[4][TN];
#pragma unroll
    for (int i = 0; i < 4; i++)
#pragma unroll
        for (int j = 0; j < TN; j++) c[i][j] = 0.0f;

    for (int k0 = 0; k0 < K; k0 += 32) {
        {
            int i = tid >> 2;
            int j0 = (tid & 3) * 8;
            long base = (m0 + i) * (long)K + k0 + j0;
#pragma unroll
            for (int jj = 0; jj < 8; jj++) As[j0 + jj][i] = ldf(A, base + jj, abf);
        }
        if (BN == 64) {
            int n = tid >> 2;
            int j0 = (tid & 3) * 8;
            long base = (long)(n0 + n) * K + k0 + j0;
#pragma unroll
            for (int jj = 0; jj < 8; jj++) Bs[j0 + jj][n] = ldf(W, base + jj, fbf);
        } else {
            int n = tid >> 3;
            int j0 = (tid & 7) * 4;
            long base = (long)(n0 + n) * K + k0 + j0;
#pragma unroll
            for (int jj = 0; jj < 4; jj++) Bs[j0 + jj][n] = ldf(W, base + jj, fbf);
        }
        __syncthreads();
#pragma unroll
        for (int kk = 0; kk < 32; kk++) {
            const float4 af = *reinterpret_cast<const float4*>(&As[kk][ty * 4]);
            const float av[4] = {af.x, af.y, af.z, af.w};
            float bv[TN];
#pragma unroll
            for (int j = 0; j < TN; j++) bv[j] = Bs[kk][tx * TN + j];
#pragma unroll
            for (int i = 0; i < 4; i++)
#pragma unroll
                for (int j = 0; j < TN; j++) c[i][j] = fmaf(av[i], bv[j], c[i][j]);
        }
        __syncthreads();
    }

#pragma unroll
    for (int i = 0; i < 4; i++) {
        long row = m0 + ty * 4 + i;
        long id = 0;
        if (EMB) id = ldix(idxp, row, i64);
#pragma unroll
        for (int j = 0; j < TN; j++) {
            int col = n0 + tx * TN + j;
            float v = c[i][j];
            if (TANH) v = tanhf(v);
            if (EMB)  v *= ldf(emb, id * (long)embN + col, fbf);
            Cout[row * (long)N + col] = v;
        }
    }
}

// ---------- fused time-shift + LayerNorm ----------
template<int DIM>
__global__ __launch_bounds__(256) void shiftln_kernel(
    const float* __restrict__ src, void* __restrict__ dst, int dst_bf16,
    const void* __restrict__ xs, const void* __restrict__ g,
    const void* __restrict__ bb, const int* __restrict__ flags)
{
    const int fbf = flags[0];
    const long r = blockIdx.x;
    const int t = (int)(r % T_);
    const int tid = threadIdx.x;
    constexpr int PT = DIM / 256;
    float m[PT];
    float s1 = 0.0f, s2 = 0.0f;
#pragma unroll
    for (int j = 0; j < PT; j++) {
        int o = tid + 256 * j;
        float v  = src[r * DIM + o];
        float pv = (t > 0) ? src[(r - 1) * DIM + o] : 0.0f;
        float xv = ldf(xs, o, fbf);
        float mm = v + (pv - v) * xv;
        m[j] = mm;
        s1 += mm;
        s2 += mm * mm;
    }
#pragma unroll
    for (int off = 32; off > 0; off >>= 1) {
        s1 += __shfl_xor(s1, off);
        s2 += __shfl_xor(s2, off);
    }
    __shared__ float r1[4], r2[4];
    int w = tid >> 6;
    if ((tid & 63) == 0) { r1[w] = s1; r2[w] = s2; }
    __syncthreads();
    float t1 = r1[0] + r1[1] + r1[2] + r1[3];
    float t2 = r2[0] + r2[1] + r2[2] + r2[3];
    float mean = t1 / (float)DIM;
    float var  = t2 / (float)DIM - mean * mean;
    float rs = rsqrtf(var + EPSF);
#pragma unroll
    for (int j = 0; j < PT; j++) {
        int o = tid + 256 * j;
        float y = (m[j] - mean) * rs * ldf(g, o, fbf) + ldf(bb, o, fbf);
        if (dst_bf16) ((unsigned short*)dst)[r * DIM + o] = f2bf(y);
        else          ((float*)dst)[r * DIM + o] = y;
    }
}

// ---------- transpose v: vpak u32[8192][512] (bf16 pairs) -> vT bf16 [B][1024][2048] ----------
__global__ __launch_bounds__(256) void vtrans_kernel(
    const unsigned* __restrict__ vpak, unsigned short* __restrict__ vT)
{
    __shared__ unsigned tile[64][33];
    const int row0 = blockIdx.x * 64;      // global row in [0, 8192)
    const int c0   = blockIdx.y * 64;      // channel base
    const int tid = threadIdx.x;
    {
        int i = tid >> 2, jg = tid & 3;
        const unsigned* src = vpak + (long)(row0 + i) * 512 + (c0 >> 1) + jg * 8;
#pragma unroll
        for (int u = 0; u < 8; u++) tile[i][jg * 8 + u] = src[u];
    }
    __syncthreads();
    const int ch = tid >> 2;               // local channel 0..63
    const int tc = (tid & 3) * 16;
    __align__(16) unsigned short buf[16];
#pragma unroll
    for (int u = 0; u < 16; u++) {
        unsigned wv = tile[tc + u][ch >> 1];
        buf[u] = (ch & 1) ? (unsigned short)(wv >> 16) : (unsigned short)(wv & 0xffffu);
    }
    const int bb = row0 / T_;
    const int t0 = row0 % T_;
    unsigned short* dst = vT + ((long)bb * C_ + c0 + ch) * T_ + t0 + tc;
    *reinterpret_cast<uint4*>(dst)     = *reinterpret_cast<const uint4*>(&buf[0]);
    *reinterpret_cast<uint4*>(dst + 8) = *reinterpret_cast<const uint4*>(&buf[8]);
}

// ---------- MFMA flash attention ----------
// 16 queries/block, 4 waves. Per 64-key tile: wave w computes S for keys
// [kt0+16w, +16) (8 MFMA), softmax (capped scores => no rescale), P -> LDS
// bf16 A-layout; then each wave does PV over its 256-channel slice (32 MFMA)
// reading vT[b][ch][t] B-frags from global.
__global__ __launch_bounds__(256) void attn_kernel(
    const unsigned short* __restrict__ q,   // bf16 [B*T][256]
    const unsigned short* __restrict__ k,   // bf16 [B*T][256]
    const unsigned short* __restrict__ vT,  // bf16 [B][1024][2048]
    float* __restrict__ out)
{
    __shared__ unsigned short ks[64 * 264]; // K tile, pitch 264 shorts (528B)
    __shared__ unsigned short ps[16 * 72];  // P tile, pitch 72 shorts (144B)
    __shared__ float dls[4][16];

    const int tid  = threadIdx.x;
    const int w    = tid >> 6;
    const int l    = tid & 63;
    const int l15  = l & 15;
    const int quad = l >> 4;

    // balance swizzle: resident pair (i, i+256) sums to ~constant work
    const int i    = blockIdx.x;
    const int half = i >> 8;
    const int r    = i & 255;
    const int tb   = half ? (127 - (r & 127)) : (r & 127);
    const int b    = (r >> 7) + 2 * half;
    const int t0   = tb * 16;

    // Q A-frags: lane holds Q[q=t0+l15][feat = 32*ii + quad*8 + j]
    bf16x8 qA[8];
    {
        const unsigned short* qrow = q + ((long)b * T_ + t0 + l15) * QD + quad * 8;
#pragma unroll
        for (int ii = 0; ii < 8; ii++)
            qA[ii] = *reinterpret_cast<const bf16x8*>(qrow + ii * 32);
    }

    f32x4 acc[16];
#pragma unroll
    for (int jt = 0; jt < 16; jt++) acc[jt] = (f32x4){0.f, 0.f, 0.f, 0.f};
    float den[4] = {0.f, 0.f, 0.f, 0.f};

    const int ntiles = t0 / 64 + 1;
    for (int tile = 0; tile < ntiles; tile++) {
        const int kt0 = tile * 64;
        __syncthreads();
        {   // stage K tile 64 x 256 bf16, coalesced
            int row = tid >> 2, seg = tid & 3;
            const unsigned short* src = k + ((long)b * T_ + kt0 + row) * QD + seg * 64;
            unsigned short* dst = ks + row * 264 + seg * 64;
#pragma unroll
            for (int u = 0; u < 8; u++)
                *reinterpret_cast<bf16x8*>(dst + u * 8) =
                    *reinterpret_cast<const bf16x8*>(src + u * 8);
        }
        __syncthreads();

        // QK^T for this wave's 16-key group
        f32x4 s = (f32x4){0.f, 0.f, 0.f, 0.f};
        {
            const unsigned short* kbase = ks + (w * 16 + l15) * 264 + quad * 8;
#pragma unroll
            for (int ii = 0; ii < 8; ii++) {
                bf16x8 kb = *reinterpret_cast<const bf16x8*>(kbase + ii * 32);
                s = __builtin_amdgcn_mfma_f32_16x16x32_bf16(qA[ii], kb, s, 0, 0, 0);
            }
        }

        // softmax weights (C-layout: row q = quad*4+rr, col key = w*16+l15)
        const int key = kt0 + w * 16 + l15;
        float wv[4];
#pragma unroll
        for (int rr = 0; rr < 4; rr++) {
            int qrow = t0 + quad * 4 + rr;
            float sc = CAPS * tanhf(s[rr] * INV_SS);
            float e = __expf(sc);
            e = (key <= qrow) ? e : 0.0f;
            wv[rr] = bf2f(f2bf(e));          // round as PV will see it
        }
        // den partial: sum over 16 keys (low-4 lane bits)
        {
            float d0 = wv[0], d1 = wv[1], d2 = wv[2], d3 = wv[3];
#pragma unroll
            for (int off = 1; off < 16; off <<= 1) {
                d0 += __shfl_xor(d0, off);
                d1 += __shfl_xor(d1, off);
                d2 += __shfl_xor(d2, off);
                d3 += __shfl_xor(d3, off);
            }
            den[0] += d0; den[1] += d1; den[2] += d2; den[3] += d3;
        }
        // write P (bf16, A-layout rows)
#pragma unroll
        for (int rr = 0; rr < 4; rr++)
            ps[(quad * 4 + rr) * 72 + w * 16 + l15] = f2bf(wv[rr]);
        __syncthreads();

        // PV: out slice [16q x 256ch], 64 keys = 2 halves of K=32
        const unsigned short* vb =
            vT + ((long)b * C_ + w * 256 + l15) * T_ + kt0 + quad * 8;
#pragma unroll
        for (int h = 0; h < 2; h++) {
            bf16x8 pA = *reinterpret_cast<const bf16x8*>(ps + l15 * 72 + h * 32 + quad * 8);
#pragma unroll
            for (int jt = 0; jt < 16; jt++) {
                bf16x8 vf = *reinterpret_cast<const bf16x8*>(vb + (long)jt * 16 * T_ + h * 32);
                acc[jt] = __builtin_amdgcn_mfma_f32_16x16x32_bf16(pA, vf, acc[jt], 0, 0, 0);
            }
        }
    }

    // combine denominators across waves
    if (l15 == 0) {
#pragma unroll
        for (int rr = 0; rr < 4; rr++) dls[w][quad * 4 + rr] = den[rr];
    }
    __syncthreads();
    float inv[4];
#pragma unroll
    for (int rr = 0; rr < 4; rr++) {
        int qr = quad * 4 + rr;
        inv[rr] = 1.0f / (dls[0][qr] + dls[1][qr] + dls[2][qr] + dls[3][qr]);
    }

    // store: acc[jt][rr] -> out[t0+quad*4+rr][w*256 + jt*16 + l15]
    float* ob = out + ((long)b * T_ + t0) * C_ + w * 256 + l15;
#pragma unroll
    for (int jt = 0; jt < 16; jt++)
#pragma unroll
        for (int rr = 0; rr < 4; rr++)
            ob[(long)(quad * 4 + rr) * C_ + jt * 16] = acc[jt][rr] * inv[rr];
}

// ---------- launch ----------
extern "C" void kernel_launch(void* const* d_in, const int* in_sizes, int n_in,
                              void* d_out, int out_size, void* d_ws, size_t ws_size,
                              hipStream_t stream) {
    const void* x       = d_in[0];
    const void* idx     = d_in[1];
    const void* W_qq    = d_in[2];
    const void* W_k     = d_in[3];
    const void* W_kup   = d_in[4];
    const void* W_v     = d_in[5];
    const void* W_vup   = d_in[6];
    const void* k_emb   = d_in[7];
    const void* v_emb   = d_in[8];
    const void* x_q     = d_in[9];
    const void* x_k     = d_in[10];
    const void* x_v     = d_in[11];
    const void* g_q     = d_in[12];
    const void* b_q     = d_in[13];
    const void* g_k     = d_in[14];
    const void* b_k     = d_in[15];
    const void* g_v     = d_in[16];
    const void* b_v     = d_in[17];

    char* p = (char*)d_ws;
    int*   flags = (int*)p;            p += 256;
    float* qraw  = (float*)p;          p += (size_t)NR * QD * 4;       // 8 MB
    float* kd    = (float*)p;          p += (size_t)NR * KVD * 4;      // 1 MB
    float* vd    = (float*)p;          p += (size_t)NR * KVD * 4;      // 1 MB
    float* kraw  = (float*)p;          p += (size_t)NR * QD * 4;       // 8 MB
    float* vraw  = (float*)p;          p += (size_t)NR * C_ * 4;       // 32 MB
    unsigned short* qf = (unsigned short*)p;  p += (size_t)NR * QD * 4; // bf16 in 8 MB slot
    unsigned short* kf = (unsigned short*)p;  p += (size_t)NR * QD * 4;
    unsigned* vpak = (unsigned*)p;     p += (size_t)NR * (C_ / 2) * 4; // 16 MB
    unsigned short* vT = (unsigned short*)vraw;  // alias: vraw dead before vtrans

    detect_kernel<<<1, 256, 0, stream>>>(x, idx, flags);

    gemm_kernel<64, 0, 0><<<dim3(NR / 64, QD / 64), 256, 0, stream>>>(
        x, W_qq, nullptr, nullptr, qraw, NR, C_, QD, 0, 1, flags);
    gemm_kernel<32, 0, 0><<<dim3(NR / 64, 1), 256, 0, stream>>>(
        x, W_k, nullptr, nullptr, kd, NR, C_, KVD, 0, 1, flags);
    gemm_kernel<32, 0, 0><<<dim3(NR / 64, 1), 256, 0, stream>>>(
        x, W_v, nullptr, nullptr, vd, NR, C_, KVD, 0, 1, flags);
    gemm_kernel<64, 0, 1><<<dim3(NR / 64, QD / 64), 256, 0, stream>>>(
        kd, W_kup, k_emb, idx, kraw, NR, KVD, QD, QD, 0, flags);
    gemm_kernel<64, 1, 1><<<dim3(NR / 64, C_ / 64), 256, 0, stream>>>(
        vd, W_vup, v_emb, idx, vraw, NR, KVD, C_, C_, 0, flags);

    shiftln_kernel<QD><<<NR, 256, 0, stream>>>(qraw, qf, 1, x_q, g_q, b_q, flags);
    shiftln_kernel<QD><<<NR, 256, 0, stream>>>(kraw, kf, 1, x_k, g_k, b_k, flags);
    shiftln_kernel<C_><<<NR, 256, 0, stream>>>(vraw, vpak, 1, x_v, g_v, b_v, flags);

    vtrans_kernel<<<dim3(NR / 64, C_ / 64), 256, 0, stream>>>(vpak, vT);

    attn_kernel<<<512, 256, 0, stream>>>(qf, kf, vT, (float*)d_out);
}